// Round 10
// baseline (58.506 us; speedup 1.0000x reference)
//
#include <hip/hip_runtime.h>

typedef __attribute__((ext_vector_type(8)))  __bf16 bf16x8;
typedef __attribute__((ext_vector_type(4)))  __bf16 bf16x4;
typedef __attribute__((ext_vector_type(16))) float  f32x16;

constexpr int NG  = 2048;
constexpr int NN  = 64;
constexpr int DD  = 128;
constexpr int KK  = 128;
constexpr int OUTD = 10;

// upper-triangular 32x32 tile list: t -> (ti, tj), ti <= tj
__device__ __host__ inline void tileOf(int t, int& ti, int& tj) {
    if (t < 4)      { ti = 0; tj = t;     }
    else if (t < 7) { ti = 1; tj = t - 3; }
    else if (t < 9) { ti = 2; tj = t - 5; }
    else            { ti = 3; tj = 3;     }
}

// XtL: 64-elem rows -> XOR elem bits 3-5 with row&7
__device__ inline int xtIdx(int r, int c) { return r * 64  + (c ^ ((r & 7) << 3)); }
// GL: 128-elem rows -> XOR elem bits 3-6 with row&15
__device__ inline int gIdx (int r, int c) { return r * 128 + (c ^ ((r & 15) << 3)); }

// ---------------------------------------------------------------------------
// Kernel 1a: A[o][f][e] = sum_k Wa[k,f]*W1[o,k*D+e]; c[o][e] = sum_k b[k]*W1[o,k*D+e]
// ---------------------------------------------------------------------------
__global__ __launch_bounds__(128)
void precompute_kernel(const float* __restrict__ Wa,
                       const float* __restrict__ b_att,
                       const float* __restrict__ W1,
                       float* __restrict__ A,
                       float* __restrict__ c)
{
    const int o = blockIdx.x >> 7;
    const int f = blockIdx.x & 127;
    const int e = threadIdx.x;
    const float* __restrict__ W1o = W1 + (size_t)o * (KK * DD);

    float acc = 0.f, cacc = 0.f;
    for (int k = 0; k < KK; ++k) {
        const float w1 = W1o[k * DD + e];
        acc  += Wa[k * DD + f] * w1;
        cacc += b_att[k] * w1;
    }
    A[((size_t)o * DD + f) * DD + e] = acc;
    if (f == 0) c[o * DD + e] = cacc;
}

// ---------------------------------------------------------------------------
// Kernel 1b (proven): symmetrized S packed in 32x32 D-fragment order, bf16,
// diag-tile upper part zeroed in memory.
//   S[f,e] = A[f,e]+A[e,f] (f<e) ; A[f,f] (f==e) ; 0 (f>e in diag tiles)
//   Sp[((o*10+t)*64 + lane)*16 + r] = S[ti*32 + (r&3)+8*(r>>2)+4*(lane>>5), tj*32 + (lane&31)]
// ---------------------------------------------------------------------------
__global__ __launch_bounds__(256)
void pack_kernel(const float* __restrict__ A, __bf16* __restrict__ Sp)
{
    const int b = blockIdx.x;
    const int o = b / 10, t = b - o * 10;
    int ti, tj; tileOf(t, ti, tj);
    const int l  = threadIdx.x & 63;
    const int rq = threadIdx.x >> 6;      // 0..3
    const int e  = tj * 32 + (l & 31);
    const float* __restrict__ Ao = A + (size_t)o * DD * DD;

    bf16x4 p;
#pragma unroll
    for (int j = 0; j < 4; ++j) {
        const int f = ti * 32 + j + 8 * rq + 4 * (l >> 5);
        float v;
        if (f < e)       v = Ao[f * DD + e] + Ao[e * DD + f];
        else if (f == e) v = Ao[f * DD + f];
        else             v = 0.f;
        p[j] = (__bf16)v;
    }
    *(bf16x4*)&Sp[(size_t)((o * 10 + t) * 64 + l) * 16 + rq * 4] = p;
}

// ---------------------------------------------------------------------------
// Kernel 2: one block per TWO graphs, 512 threads = 8 waves, 6 barriers.
// LDS: lds48 raw 48 KB: XtL [0,16K) | GL [16K,48K); PP (40 KB, phases 4-5)
//      aliases XtL+GL. sp 4 KB, sA/sB 1 KB -> 54272 B total.
// Schedule: ph0A |B1| ph1A+ph2A |B2| (ldB ; colsumA ; ph3A ; stB) |B3|
//           ph1B+ph2B |B4| (colsumB ; ph3B) |B5| ph4 |B6| ph5.
// Extra H-tiles 8,9: graph A on waves 6,7; graph B on waves 4,5 (shared hX1).
// ---------------------------------------------------------------------------
__global__ __launch_bounds__(512, 2)
void graph_kernel(const float* __restrict__ x,
                  const __bf16* __restrict__ Sp,
                  const float* __restrict__ cg,
                  const float* __restrict__ bias1,
                  float* __restrict__ out)
{
    __shared__ __align__(16) char lds48[48 * 1024];
    __shared__ float sp[8][DD];                           // 4 KB
    __shared__ float sA[DD], sB[DD];

    __bf16* const XtL = (__bf16*)lds48;                   // 16 KB
    __bf16* const GL  = (__bf16*)(lds48 + 16 * 1024);     // 32 KB
    float*  const PP  = (float*)lds48;                    // 40 KB (ph4/5)

    const int g0  = blockIdx.x * 2;
    const int g1  = g0 + 1;
    const int tid = threadIdx.x;
    const int w   = tid >> 6;
    const int l   = tid & 63;
    const int l31 = l & 31;
    const int l5  = l >> 5;
    const int f   = tid & 127, half = tid >> 7;
    const float* __restrict__ xgA = x + (size_t)g0 * NN * DD;
    const float* __restrict__ xgB = x + (size_t)g1 * NN * DD;

    const int ti  = w & 3;
    const int tj0 = (w >> 2) * 2;

    // ---- ph0A: load A's X column-wise, store X^T bf16 ----
    {
#pragma unroll
        for (int ch = 0; ch < 2; ++ch) {
            float v[8];
#pragma unroll
            for (int i = 0; i < 8; ++i) v[i] = xgA[(half * 16 + ch * 8 + i) * DD + f];
            bf16x8 p;
#pragma unroll
            for (int i = 0; i < 8; ++i) p[i] = (__bf16)v[i];
            *(bf16x8*)&XtL[xtIdx(f, half * 16 + ch * 8)] = p;
        }
    }
    __syncthreads();   // B1: XtL(A) ready

    f32x16 hA0, hB0, hX1;
#pragma unroll
    for (int i = 0; i < 16; ++i) hX1[i] = 0.f;

    // ---- ph1A: gram MFMA ---- (no barrier into ph2A: GL disjoint from XtL)
    f32x16 acc0, acc1;
#pragma unroll
    for (int i = 0; i < 16; ++i) { acc0[i] = 0.f; acc1[i] = 0.f; }
    {
        const int arow  = ti  * 32 + l31;
        const int brow0 = tj0 * 32 + l31;
#pragma unroll
        for (int ks = 0; ks < 4; ++ks) {
            const int kc = ks * 16 + l5 * 8;
            bf16x8 a  = *(const bf16x8*)&XtL[xtIdx(arow, kc)];
            bf16x8 b0 = *(const bf16x8*)&XtL[xtIdx(brow0, kc)];
            bf16x8 b1 = *(const bf16x8*)&XtL[xtIdx(brow0 + 32, kc)];
            acc0 = __builtin_amdgcn_mfma_f32_32x32x16_bf16(a, b0, acc0, 0, 0, 0);
            acc1 = __builtin_amdgcn_mfma_f32_32x32x16_bf16(a, b1, acc1, 0, 0, 0);
        }
    }
    // ---- ph2A: quantize -> GL (transposed) + sp partials ----
    {
        float sum0 = 0.f, sum1 = 0.f;
#pragma unroll
        for (int tt = 0; tt < 2; ++tt) {
            const int e = (tj0 + tt) * 32 + l31;
#pragma unroll
            for (int g2 = 0; g2 < 4; ++g2) {
                bf16x4 p;
#pragma unroll
                for (int j = 0; j < 4; ++j) {
                    const float av = tt ? acc1[g2 * 4 + j] : acc0[g2 * 4 + j];
                    const float q = rintf(av * 100.f) * 0.01f;
                    p[j] = (__bf16)q;
                    if (tt) sum1 += q; else sum0 += q;
                }
                *(bf16x4*)&GL[gIdx(e, ti * 32 + g2 * 8 + l5 * 4)] = p;
            }
        }
        sp[ti * 2 + l5][tj0 * 32 + l31]       = sum0;
        sp[ti * 2 + l5][(tj0 + 1) * 32 + l31] = sum1;
    }
    __syncthreads();   // B2: G(A)+sp ready; XtL(A) reads done

    // ---- segment: ph0B loads ; colsumA ; ph3A ; ph0B store ----
    float vB[16];
#pragma unroll
    for (int i = 0; i < 16; ++i) vB[i] = xgB[(half * 16 + i) * DD + f];

    if (w == 2 || w == 3) {
        const int e = (w - 2) * 64 + l;
        float s = 0.f;
#pragma unroll
        for (int i = 0; i < 8; ++i) s += sp[i][e];
        sA[e] = s;
    }

#pragma unroll
    for (int i = 0; i < 16; ++i) hA0[i] = 0.f;
    {
        int hti, htj; tileOf(w, hti, htj);
        const int ra = hti * 32 + l31, rb = htj * 32 + l31;
#pragma unroll
        for (int ks = 0; ks < 8; ++ks) {
            const int kc = ks * 16 + l5 * 8;
            bf16x8 a = *(const bf16x8*)&GL[gIdx(ra, kc)];
            bf16x8 b = *(const bf16x8*)&GL[gIdx(rb, kc)];
            hA0 = __builtin_amdgcn_mfma_f32_32x32x16_bf16(a, b, hA0, 0, 0, 0);
        }
    }
    if (w >= 6) {
        int ti1, tj1; tileOf(8 + (w - 6), ti1, tj1);
        const int ra = ti1 * 32 + l31, rb = tj1 * 32 + l31;
#pragma unroll
        for (int ks = 0; ks < 8; ++ks) {
            const int kc = ks * 16 + l5 * 8;
            bf16x8 a = *(const bf16x8*)&GL[gIdx(ra, kc)];
            bf16x8 b = *(const bf16x8*)&GL[gIdx(rb, kc)];
            hX1 = __builtin_amdgcn_mfma_f32_32x32x16_bf16(a, b, hX1, 0, 0, 0);
        }
    }
    {
        bf16x8 p0, p1;
#pragma unroll
        for (int i = 0; i < 8; ++i) { p0[i] = (__bf16)vB[i]; p1[i] = (__bf16)vB[8 + i]; }
        *(bf16x8*)&XtL[xtIdx(f, half * 16)]     = p0;
        *(bf16x8*)&XtL[xtIdx(f, half * 16 + 8)] = p1;
    }
    __syncthreads();   // B3: GL(A) reads done; XtL(B) ready; sA visible

    // ---- ph1B + ph2B ----
#pragma unroll
    for (int i = 0; i < 16; ++i) { acc0[i] = 0.f; acc1[i] = 0.f; }
    {
        const int arow  = ti  * 32 + l31;
        const int brow0 = tj0 * 32 + l31;
#pragma unroll
        for (int ks = 0; ks < 4; ++ks) {
            const int kc = ks * 16 + l5 * 8;
            bf16x8 a  = *(const bf16x8*)&XtL[xtIdx(arow, kc)];
            bf16x8 b0 = *(const bf16x8*)&XtL[xtIdx(brow0, kc)];
            bf16x8 b1 = *(const bf16x8*)&XtL[xtIdx(brow0 + 32, kc)];
            acc0 = __builtin_amdgcn_mfma_f32_32x32x16_bf16(a, b0, acc0, 0, 0, 0);
            acc1 = __builtin_amdgcn_mfma_f32_32x32x16_bf16(a, b1, acc1, 0, 0, 0);
        }
    }
    {
        float sum0 = 0.f, sum1 = 0.f;
#pragma unroll
        for (int tt = 0; tt < 2; ++tt) {
            const int e = (tj0 + tt) * 32 + l31;
#pragma unroll
            for (int g2 = 0; g2 < 4; ++g2) {
                bf16x4 p;
#pragma unroll
                for (int j = 0; j < 4; ++j) {
                    const float av = tt ? acc1[g2 * 4 + j] : acc0[g2 * 4 + j];
                    const float q = rintf(av * 100.f) * 0.01f;
                    p[j] = (__bf16)q;
                    if (tt) sum1 += q; else sum0 += q;
                }
                *(bf16x4*)&GL[gIdx(e, ti * 32 + g2 * 8 + l5 * 4)] = p;
            }
        }
        sp[ti * 2 + l5][tj0 * 32 + l31]       = sum0;
        sp[ti * 2 + l5][(tj0 + 1) * 32 + l31] = sum1;
    }
    __syncthreads();   // B4: G(B)+sp ready

    // ---- colsumB ; ph3B ----
    if (w == 2 || w == 3) {
        const int e = (w - 2) * 64 + l;
        float s = 0.f;
#pragma unroll
        for (int i = 0; i < 8; ++i) s += sp[i][e];
        sB[e] = s;
    }
#pragma unroll
    for (int i = 0; i < 16; ++i) hB0[i] = 0.f;
    {
        int hti, htj; tileOf(w, hti, htj);
        const int ra = hti * 32 + l31, rb = htj * 32 + l31;
#pragma unroll
        for (int ks = 0; ks < 8; ++ks) {
            const int kc = ks * 16 + l5 * 8;
            bf16x8 a = *(const bf16x8*)&GL[gIdx(ra, kc)];
            bf16x8 b = *(const bf16x8*)&GL[gIdx(rb, kc)];
            hB0 = __builtin_amdgcn_mfma_f32_32x32x16_bf16(a, b, hB0, 0, 0, 0);
        }
    }
    if (w == 4 || w == 5) {
        int ti1, tj1; tileOf(8 + (w - 4), ti1, tj1);
        const int ra = ti1 * 32 + l31, rb = tj1 * 32 + l31;
#pragma unroll
        for (int ks = 0; ks < 8; ++ks) {
            const int kc = ks * 16 + l5 * 8;
            bf16x8 a = *(const bf16x8*)&GL[gIdx(ra, kc)];
            bf16x8 b = *(const bf16x8*)&GL[gIdx(rb, kc)];
            hX1 = __builtin_amdgcn_mfma_f32_32x32x16_bf16(a, b, hX1, 0, 0, 0);
        }
    }
    __syncthreads();   // B5: GL(B) reads done -> PP region free; sB visible

    // ---- ph4: contraction, o in batches of 2 (loads batched ahead) ----
    {
        float cgv[2 * OUTD];
        if (w == 0) {
#pragma unroll
            for (int o = 0; o < OUTD; ++o) {
                cgv[2 * o]     = cg[o * DD + l];
                cgv[2 * o + 1] = cg[o * DD + 64 + l];
            }
        }
        const __bf16* __restrict__ SpM = Sp + (size_t)(w * 64 + l) * 16;
        const __bf16* __restrict__ SpX = Sp + (size_t)((8 + (w & 1)) * 64 + l) * 16;
        const float sAl = sA[l], sAh = sA[64 + l];
        const float sBl = sB[l], sBh = sB[64 + l];

#pragma unroll
        for (int ob = 0; ob < 5; ++ob) {
            const int o0 = 2 * ob, o1 = 2 * ob + 1;
            // batched loads (all 4-8 in flight before FMA chains)
            const bf16x8 m0a = *(const bf16x8*)&SpM[(size_t)o0 * 10240];
            const bf16x8 m0b = *(const bf16x8*)&SpM[(size_t)o0 * 10240 + 8];
            const bf16x8 m1a = *(const bf16x8*)&SpM[(size_t)o1 * 10240];
            const bf16x8 m1b = *(const bf16x8*)&SpM[(size_t)o1 * 10240 + 8];
            bf16x8 x0a, x0b, x1a, x1b;
            if (w >= 4) {
                x0a = *(const bf16x8*)&SpX[(size_t)o0 * 10240];
                x0b = *(const bf16x8*)&SpX[(size_t)o0 * 10240 + 8];
                x1a = *(const bf16x8*)&SpX[(size_t)o1 * 10240];
                x1b = *(const bf16x8*)&SpX[(size_t)o1 * 10240 + 8];
            }
            float tA0 = 0.f, tB0 = 0.f, tA1 = 0.f, tB1 = 0.f;
#pragma unroll
            for (int j = 0; j < 8; ++j) {
                const float v0 = (float)m0a[j], v1 = (float)m1a[j];
                tA0 += v0 * hA0[j];      tB0 += v0 * hB0[j];
                tA1 += v1 * hA0[j];      tB1 += v1 * hB0[j];
            }
#pragma unroll
            for (int j = 0; j < 8; ++j) {
                const float v0 = (float)m0b[j], v1 = (float)m1b[j];
                tA0 += v0 * hA0[8 + j];  tB0 += v0 * hB0[8 + j];
                tA1 += v1 * hA0[8 + j];  tB1 += v1 * hB0[8 + j];
            }
            if (w >= 4) {
                float tx0 = 0.f, tx1 = 0.f;
#pragma unroll
                for (int j = 0; j < 8; ++j) {
                    tx0 += (float)x0a[j] * hX1[j];
                    tx1 += (float)x1a[j] * hX1[j];
                }
#pragma unroll
                for (int j = 0; j < 8; ++j) {
                    tx0 += (float)x0b[j] * hX1[8 + j];
                    tx1 += (float)x1b[j] * hX1[8 + j];
                }
                if (w >= 6) { tA0 += tx0; tA1 += tx1; }
                else        { tB0 += tx0; tB1 += tx1; }
            }
            if (w == 0) {
                tA0 += cgv[2 * o0] * sAl + cgv[2 * o0 + 1] * sAh;
                tB0 += cgv[2 * o0] * sBl + cgv[2 * o0 + 1] * sBh;
                tA1 += cgv[2 * o1] * sAl + cgv[2 * o1 + 1] * sAh;
                tB1 += cgv[2 * o1] * sBl + cgv[2 * o1 + 1] * sBh;
            }
            PP[o0 * 512 + tid]        = tA0;
            PP[(10 + o0) * 512 + tid] = tB0;
            PP[o1 * 512 + tid]        = tA1;
            PP[(10 + o1) * 512 + tid] = tB1;
        }
    }
    __syncthreads();   // B6

    // ---- ph5: 20 reduce instances over 8 waves ----
    for (int p = w; p < 2 * OUTD; p += 8) {
        const float4 q0 = *(const float4*)&PP[p * 512 + l * 8];
        const float4 q1 = *(const float4*)&PP[p * 512 + l * 8 + 4];
        float v = (q0.x + q0.y) + (q0.z + q0.w) + (q1.x + q1.y) + (q1.z + q1.w);
        v += __shfl_down(v, 32, 64);
        v += __shfl_down(v, 16, 64);
        v += __shfl_down(v, 8, 64);
        v += __shfl_down(v, 4, 64);
        v += __shfl_down(v, 2, 64);
        v += __shfl_down(v, 1, 64);
        if (l == 0) {
            const int gg = (p < OUTD) ? g0 : g1;
            const int oo = (p < OUTD) ? p : p - OUTD;
            out[(size_t)gg * OUTD + oo] = v + bias1[oo];
        }
    }
}

// ---------------------------------------------------------------------------
extern "C" void kernel_launch(void* const* d_in, const int* in_sizes, int n_in,
                              void* d_out, int out_size, void* d_ws, size_t ws_size,
                              hipStream_t stream)
{
    const float* x     = (const float*)d_in[0];
    const float* Wa    = (const float*)d_in[1];
    const float* b_att = (const float*)d_in[2];
    const float* W1    = (const float*)d_in[3];
    const float* bias1 = (const float*)d_in[4];
    float* out = (float*)d_out;

    float*  A  = (float*)d_ws;                       // 163840 f32 (640 KB)
    float*  c  = A + (size_t)OUTD * DD * DD;         // 1280 f32
    __bf16* Sp = (__bf16*)(c + OUTD * DD);           // 102400 bf16 (200 KB)

    precompute_kernel<<<OUTD * DD, 128, 0, stream>>>(Wa, b_att, W1, A, c);
    pack_kernel<<<100, 256, 0, stream>>>(A, Sp);
    graph_kernel<<<NG / 2, 512, 0, stream>>>(x, Sp, c, bias1, out);
}